// Round 8
// baseline (170.210 us; speedup 1.0000x reference)
//
#include <hip/hip_runtime.h>

#define N_NODES 50000
#define N_EDGES 600000
#define DIN 128
#define HD 128
#define DOUT 64
#define SCAN_BLOCKS 196  // ceil(50000/256)

typedef float f32x4 __attribute__((ext_vector_type(4)));
typedef short bf16x8 __attribute__((ext_vector_type(8)));

__device__ __forceinline__ unsigned short f2bf(float f) {
    unsigned u = __float_as_uint(f);
    unsigned r = (u + 0x7FFFu + ((u >> 16) & 1u)) >> 16;
    return (unsigned short)r;
}
__device__ __forceinline__ float bf2f(unsigned short s) {
    return __uint_as_float(((unsigned)s) << 16);
}

// ---------------- merged prep: xcvt (6250 blk) | zero degi (196) | bprep (192)
__global__ __launch_bounds__(256) void prep_kernel(const float* __restrict__ x,
                                                   unsigned short* __restrict__ xb,
                                                   int* __restrict__ degi,
                                                   const float* __restrict__ w1l,
                                                   const float* __restrict__ w1r,
                                                   const float* __restrict__ w2l,
                                                   const float* __restrict__ w2r,
                                                   unsigned short* __restrict__ bfr) {
    int gid = blockIdx.x;
    if (gid < 6250) {                    // x -> bf16, exact
        int i = gid * 256 + threadIdx.x;
        float4 v = ((const float4*)x)[i];
        ushort4 o;
        o.x = f2bf(v.x); o.y = f2bf(v.y); o.z = f2bf(v.z); o.w = f2bf(v.w);
        ((ushort4*)xb)[i] = o;
    } else if (gid < 6250 + 196) {       // zero degi
        int i = (gid - 6250) * 256 + threadIdx.x;
        if (i < N_NODES) degi[i] = 0;
    } else {                             // weight fragment prep
        int tid = (gid - 6446) * 256 + threadIdx.x;  // < 3*16384
        int a = tid >> 14;
        int r = tid & 16383;
        int j = r & 7, lane = (r >> 3) & 63, kc = (r >> 9) & 3, ct = r >> 11;
        int k = kc * 32 + ((lane >> 4) << 3) + j;
        int c = (ct << 4) + (lane & 15);
        float v;
        if (a == 0) v = w1l[k * HD + c];
        else if (a == 1) v = w1r[k * HD + c];
        else v = (c < 64) ? w2l[k * DOUT + c] : w2r[k * DOUT + (c - 64)];
        bfr[tid] = f2bf(v);
    }
}

// ---------------- degree histogram (int) ----------------
__global__ __launch_bounds__(256) void deg_kernel(const int* __restrict__ ei,
                                                  int* __restrict__ degi) {
    int e = blockIdx.x * 256 + threadIdx.x;
    if (e < N_EDGES) atomicAdd(&degi[ei[N_EDGES + e]], 1);
}

// ---------------- scan phase A: per-block (256-elem) sums ----------------
__global__ __launch_bounds__(256) void scanA_kernel(const int* __restrict__ degi,
                                                    int* __restrict__ partial) {
    int i = blockIdx.x * 256 + threadIdx.x;
    int v = (i < N_NODES) ? degi[i] : 0;
#pragma unroll
    for (int off = 32; off > 0; off >>= 1) v += __shfl_down(v, (unsigned)off, 64);
    __shared__ int ws[4];
    const int lane = threadIdx.x & 63, wid = threadIdx.x >> 6;
    if (lane == 0) ws[wid] = v;
    __syncthreads();
    if (threadIdx.x == 0) partial[blockIdx.x] = ws[0] + ws[1] + ws[2] + ws[3];
}

// ---------------- scan phase B: 1 block scans the partials ----------------
__global__ __launch_bounds__(256) void scanB_kernel(int* __restrict__ partial,
                                                    int* __restrict__ row_ptr) {
    const int lane = threadIdx.x & 63, wid = threadIdx.x >> 6;
    int i = threadIdx.x;
    int v = (i < SCAN_BLOCKS) ? partial[i] : 0;
    int incl = v;
#pragma unroll
    for (int off = 1; off < 64; off <<= 1) {
        int t = __shfl_up(incl, (unsigned)off, 64);
        if (lane >= off) incl += t;
    }
    __shared__ int ws[4];
    if (lane == 63) ws[wid] = incl;
    __syncthreads();
    int woff = 0;
    for (int w = 0; w < wid; w++) woff += ws[w];
    incl += woff;
    if (i < SCAN_BLOCKS) partial[i] = incl - v;
    if (i == 255) row_ptr[N_NODES] = incl;
}

// ---------------- scan phase C: local scan + block offset ----------------
__global__ __launch_bounds__(256) void scanC_kernel(const int* __restrict__ degi,
                                                    const int* __restrict__ partial,
                                                    int* __restrict__ row_ptr,
                                                    int* __restrict__ cursor) {
    const int lane = threadIdx.x & 63, wid = threadIdx.x >> 6;
    int i = blockIdx.x * 256 + threadIdx.x;
    int v = (i < N_NODES) ? degi[i] : 0;
    int incl = v;
#pragma unroll
    for (int off = 1; off < 64; off <<= 1) {
        int t = __shfl_up(incl, (unsigned)off, 64);
        if (lane >= off) incl += t;
    }
    __shared__ int ws[4];
    if (lane == 63) ws[wid] = incl;
    __syncthreads();
    int woff = 0;
    for (int w = 0; w < wid; w++) woff += ws[w];
    int excl = partial[blockIdx.x] + woff + incl - v;
    if (i < N_NODES) { row_ptr[i] = excl; cursor[i] = excl; }
}

// ---------------- CSR fill ----------------
__global__ __launch_bounds__(256) void fill_kernel(const int* __restrict__ ei,
                                                   int* __restrict__ cursor,
                                                   int* __restrict__ csr) {
    int e = blockIdx.x * 256 + threadIdx.x;
    if (e < N_EDGES) {
        int s = ei[e];
        int t = ei[N_EDGES + e];
        int pos = atomicAdd(&cursor[t], 1);
        csr[pos] = s;
    }
}

// ---------------- gather layer-1: 4 edge slots x 2 edges in flight (R6-proven)
__global__ __launch_bounds__(256) void gather1_kernel(const int* __restrict__ row_ptr,
                                                      const int* __restrict__ csr,
                                                      const unsigned short* __restrict__ xb,
                                                      float* __restrict__ mean) {
    int node = blockIdx.x * 4 + (threadIdx.x >> 6);
    if (node >= N_NODES) return;
    const int lane = threadIdx.x & 63;
    const int g = lane >> 4;   // edge slot 0..3
    const int sl = lane & 15;  // dims [8*sl, 8*sl+8)
    int beg = row_ptr[node], end = row_ptr[node + 1];
    float acc[8] = {0.f, 0.f, 0.f, 0.f, 0.f, 0.f, 0.f, 0.f};
    int base = beg + g;
    for (; base + 4 < end; base += 8) {  // two independent loads per iter (MLP=2)
        int s0 = csr[base];
        int s1 = csr[base + 4];
        uint4 u0 = *(const uint4*)(xb + (size_t)s0 * DIN + sl * 8);
        uint4 u1 = *(const uint4*)(xb + (size_t)s1 * DIN + sl * 8);
        acc[0] += __uint_as_float(u0.x << 16) + __uint_as_float(u1.x << 16);
        acc[1] += __uint_as_float(u0.x & 0xffff0000u) + __uint_as_float(u1.x & 0xffff0000u);
        acc[2] += __uint_as_float(u0.y << 16) + __uint_as_float(u1.y << 16);
        acc[3] += __uint_as_float(u0.y & 0xffff0000u) + __uint_as_float(u1.y & 0xffff0000u);
        acc[4] += __uint_as_float(u0.z << 16) + __uint_as_float(u1.z << 16);
        acc[5] += __uint_as_float(u0.z & 0xffff0000u) + __uint_as_float(u1.z & 0xffff0000u);
        acc[6] += __uint_as_float(u0.w << 16) + __uint_as_float(u1.w << 16);
        acc[7] += __uint_as_float(u0.w & 0xffff0000u) + __uint_as_float(u1.w & 0xffff0000u);
    }
    if (base < end) {
        int s0 = csr[base];
        uint4 u = *(const uint4*)(xb + (size_t)s0 * DIN + sl * 8);
        acc[0] += __uint_as_float(u.x << 16);
        acc[1] += __uint_as_float(u.x & 0xffff0000u);
        acc[2] += __uint_as_float(u.y << 16);
        acc[3] += __uint_as_float(u.y & 0xffff0000u);
        acc[4] += __uint_as_float(u.z << 16);
        acc[5] += __uint_as_float(u.z & 0xffff0000u);
        acc[6] += __uint_as_float(u.w << 16);
        acc[7] += __uint_as_float(u.w & 0xffff0000u);
    }
#pragma unroll
    for (int i = 0; i < 8; i++) {
        acc[i] += __shfl_xor(acc[i], 16, 64);
        acc[i] += __shfl_xor(acc[i], 32, 64);
    }
    float r0, r1;
    if (g == 0)      { r0 = acc[0]; r1 = acc[1]; }
    else if (g == 1) { r0 = acc[2]; r1 = acc[3]; }
    else if (g == 2) { r0 = acc[4]; r1 = acc[5]; }
    else             { r0 = acc[6]; r1 = acc[7]; }
    float invd = 1.0f / fmaxf((float)(end - beg), 1.0f);
    float2 r; r.x = r0 * invd; r.y = r1 * invd;
    *(float2*)(mean + (size_t)node * DIN + sl * 8 + g * 2) = r;
}

// ---------------- fused MFMA (R6 structure + B staged in LDS w/ reg prefetch)
// h=relu(mean@w1l + x@w1r + b1); p=h@w2l; out=h@w2r+b2
__global__ __launch_bounds__(256) void fused_kernel(
    const float* __restrict__ mean, const float* __restrict__ x,
    const unsigned short* __restrict__ B1a, const unsigned short* __restrict__ B1b,
    const unsigned short* __restrict__ B2,
    const float* __restrict__ b1, const float* __restrict__ b2,
    unsigned short* __restrict__ pb, float* __restrict__ out) {
    __shared__ unsigned short Ahi[64 * 128];   // 16 KB
    __shared__ unsigned short Alo[64 * 128];   // 16 KB
    __shared__ unsigned short Bs[16384];       // 32 KB: current phase's B frags
    const int block0 = blockIdx.x * 64;
    const int tid = threadIdx.x;
    const int lane = tid & 63;
    const int wtile = tid >> 6;

    // --- issue global loads for both A-tiles up-front (registers) ---
    float4 mv[8], xv[8];
#pragma unroll
    for (int i = 0; i < 8; i++) {
        int f = tid + i * 256;
        int row = f >> 5;
        int c4 = f & 31;
        int rg = block0 + row;
        if (rg >= N_NODES) rg = N_NODES - 1;
        mv[i] = *(const float4*)(mean + (size_t)rg * 128 + c4 * 4);
        xv[i] = *(const float4*)(x + (size_t)rg * 128 + c4 * 4);
    }
    // --- B1a prefetch into registers (32 KB block-wide, 128 B/thread) ---
    uint4 rb[8];
#pragma unroll
    for (int i = 0; i < 8; i++) rb[i] = ((const uint4*)B1a)[tid + i * 256];

    f32x4 acc[8];
#pragma unroll
    for (int t = 0; t < 8; t++) acc[t] = (f32x4){0.f, 0.f, 0.f, 0.f};

    auto write_tile = [&](const float4* v8) {
#pragma unroll
        for (int i = 0; i < 8; i++) {
            int f = tid + i * 256;
            int row = f >> 5;
            int c4 = f & 31;
            float4 v = v8[i];
            ushort4 hi, lo;
            hi.x = f2bf(v.x); lo.x = f2bf(v.x - bf2f(hi.x));
            hi.y = f2bf(v.y); lo.y = f2bf(v.y - bf2f(hi.y));
            hi.z = f2bf(v.z); lo.z = f2bf(v.z - bf2f(hi.z));
            hi.w = f2bf(v.w); lo.w = f2bf(v.w - bf2f(hi.w));
            int byte = row * 256 + ((c4 * 8) ^ ((row & 7) << 4));
            *(ushort4*)((char*)Ahi + byte) = hi;
            *(ushort4*)((char*)Alo + byte) = lo;
        }
    };
    auto write_B = [&]() {
#pragma unroll
        for (int i = 0; i < 8; i++) ((uint4*)Bs)[tid + i * 256] = rb[i];
    };
    auto compute = [&]() {  // reads Ahi/Alo + Bs
        const int arow = wtile * 16 + (lane & 15);
        const int swz = (arow & 7) << 4;
#pragma unroll
        for (int kc = 0; kc < 4; kc++) {
            int byte = arow * 256 + ((kc * 64 + ((lane >> 4) << 4)) ^ swz);
            bf16x8 ahi = *(const bf16x8*)((const char*)Ahi + byte);
            bf16x8 alo = *(const bf16x8*)((const char*)Alo + byte);
#pragma unroll
            for (int ct = 0; ct < 8; ct++) {
                bf16x8 b = *(const bf16x8*)(Bs + ((((ct << 2) + kc) << 6) + lane) * 8);
                acc[ct] = __builtin_amdgcn_mfma_f32_16x16x32_bf16(ahi, b, acc[ct], 0, 0, 0);
                acc[ct] = __builtin_amdgcn_mfma_f32_16x16x32_bf16(alo, b, acc[ct], 0, 0, 0);
            }
        }
    };

    write_tile(mv);
    write_B();                       // B1a regs -> LDS
    __syncthreads();
#pragma unroll
    for (int i = 0; i < 8; i++) rb[i] = ((const uint4*)B1b)[tid + i * 256];  // prefetch B1b
    compute();                       // mean @ w1l   (B1b loads in flight)
    __syncthreads();
    write_tile(xv);
    write_B();                       // B1b regs -> LDS
    __syncthreads();
#pragma unroll
    for (int i = 0; i < 8; i++) rb[i] = ((const uint4*)B2)[tid + i * 256];   // prefetch B2
    compute();                       // + x @ w1r    (B2 loads in flight)
    __syncthreads();

    // epilogue 1: h = relu(acc + b1) -> restage as bf16 hi/lo A-tile
    {
        const int r0 = wtile * 16 + ((lane >> 4) << 2);
#pragma unroll
        for (int ct = 0; ct < 8; ct++) {
            int col = (ct << 4) + (lane & 15);
            float bv = b1[col];
#pragma unroll
            for (int r = 0; r < 4; r++) {
                float v = fmaxf(acc[ct][r] + bv, 0.f);
                unsigned short hi = f2bf(v);
                unsigned short lo = f2bf(v - bf2f(hi));
                int row = r0 + r;
                int byte = row * 256 + ((col * 2) ^ ((row & 7) << 4));
                *(unsigned short*)((char*)Ahi + byte) = hi;
                *(unsigned short*)((char*)Alo + byte) = lo;
            }
            acc[ct] = (f32x4){0.f, 0.f, 0.f, 0.f};
        }
    }
    write_B();                       // B2 regs -> LDS
    __syncthreads();
    compute();                       // h @ [w2l | w2r]

    // epilogue 2: cols 0-63 -> pb (bf16), cols 64-127 -> out (+b2, f32)
    {
        const int r0 = wtile * 16 + ((lane >> 4) << 2);
#pragma unroll
        for (int ct = 0; ct < 8; ct++) {
            int col = (ct << 4) + (lane & 15);
#pragma unroll
            for (int r = 0; r < 4; r++) {
                int node = block0 + r0 + r;
                if (node < N_NODES) {
                    if (ct < 4) pb[(size_t)node * DOUT + col] = f2bf(acc[ct][r]);
                    else out[(size_t)node * DOUT + (col - 64)] = acc[ct][r] + b2[col - 64];
                }
            }
        }
    }
}

// ---------------- gather layer-2: 8 edge slots x 2 edges in flight (R6-proven)
__global__ __launch_bounds__(256) void gather2_kernel(const int* __restrict__ row_ptr,
                                                      const int* __restrict__ csr,
                                                      const unsigned short* __restrict__ pb,
                                                      float* __restrict__ out) {
    int node = blockIdx.x * 4 + (threadIdx.x >> 6);
    if (node >= N_NODES) return;
    const int lane = threadIdx.x & 63;
    const int g = lane >> 3;  // edge slot 0..7
    const int sl = lane & 7;  // dims [8*sl, 8*sl+8)
    int beg = row_ptr[node], end = row_ptr[node + 1];
    float acc[8] = {0.f, 0.f, 0.f, 0.f, 0.f, 0.f, 0.f, 0.f};
    int base = beg + g;
    for (; base + 8 < end; base += 16) {  // two independent loads per iter
        int s0 = csr[base];
        int s1 = csr[base + 8];
        uint4 u0 = *(const uint4*)(pb + (size_t)s0 * DOUT + sl * 8);
        uint4 u1 = *(const uint4*)(pb + (size_t)s1 * DOUT + sl * 8);
        acc[0] += __uint_as_float(u0.x << 16) + __uint_as_float(u1.x << 16);
        acc[1] += __uint_as_float(u0.x & 0xffff0000u) + __uint_as_float(u1.x & 0xffff0000u);
        acc[2] += __uint_as_float(u0.y << 16) + __uint_as_float(u1.y << 16);
        acc[3] += __uint_as_float(u0.y & 0xffff0000u) + __uint_as_float(u1.y & 0xffff0000u);
        acc[4] += __uint_as_float(u0.z << 16) + __uint_as_float(u1.z << 16);
        acc[5] += __uint_as_float(u0.z & 0xffff0000u) + __uint_as_float(u1.z & 0xffff0000u);
        acc[6] += __uint_as_float(u0.w << 16) + __uint_as_float(u1.w << 16);
        acc[7] += __uint_as_float(u0.w & 0xffff0000u) + __uint_as_float(u1.w & 0xffff0000u);
    }
    if (base < end) {
        int s0 = csr[base];
        uint4 u = *(const uint4*)(pb + (size_t)s0 * DOUT + sl * 8);
        acc[0] += __uint_as_float(u.x << 16);
        acc[1] += __uint_as_float(u.x & 0xffff0000u);
        acc[2] += __uint_as_float(u.y << 16);
        acc[3] += __uint_as_float(u.y & 0xffff0000u);
        acc[4] += __uint_as_float(u.z << 16);
        acc[5] += __uint_as_float(u.z & 0xffff0000u);
        acc[6] += __uint_as_float(u.w << 16);
        acc[7] += __uint_as_float(u.w & 0xffff0000u);
    }
#pragma unroll
    for (int i = 0; i < 8; i++) {
        acc[i] += __shfl_xor(acc[i], 8, 64);
        acc[i] += __shfl_xor(acc[i], 16, 64);
        acc[i] += __shfl_xor(acc[i], 32, 64);
    }
    float r;
    if (g == 0)      r = acc[0];
    else if (g == 1) r = acc[1];
    else if (g == 2) r = acc[2];
    else if (g == 3) r = acc[3];
    else if (g == 4) r = acc[4];
    else if (g == 5) r = acc[5];
    else if (g == 6) r = acc[6];
    else             r = acc[7];
    float invd = 1.0f / fmaxf((float)(end - beg), 1.0f);
    int d = sl * 8 + g;
    out[(size_t)node * DOUT + d] += r * invd;
}

extern "C" void kernel_launch(void* const* d_in, const int* in_sizes, int n_in,
                              void* d_out, int out_size, void* d_ws, size_t ws_size,
                              hipStream_t stream) {
    const float* x   = (const float*)d_in[0];
    const int*   ei  = (const int*)d_in[1];
    const float* w1l = (const float*)d_in[2];
    const float* b1  = (const float*)d_in[3];
    const float* w1r = (const float*)d_in[4];
    const float* w2l = (const float*)d_in[5];
    const float* b2  = (const float*)d_in[6];
    const float* w2r = (const float*)d_in[7];
    float* out = (float*)d_out;

    // workspace layout
    int* iw = (int*)d_ws;
    int* degi    = iw;                        // 50000
    int* row_ptr = iw + 50000;                // 50001
    int* cursor  = iw + 100001;               // 50000
    int* csr     = iw + 150001;               // 600000
    int* partial = iw + 750001;               // 256
    float* mean  = (float*)(iw + 750272);     // N*128 f32, 16B aligned
    unsigned short* xb  = (unsigned short*)(mean + (size_t)N_NODES * DIN);  // N*128 bf16
    unsigned short* pbb = xb + (size_t)N_NODES * DIN;                       // N*64 bf16
    unsigned short* bfr = pbb + (size_t)N_NODES * DOUT;                     // 3*16384 bf16
    const unsigned short* B1a = bfr;
    const unsigned short* B1b = bfr + 16384;
    const unsigned short* B2  = bfr + 32768;

    prep_kernel<<<6638, 256, 0, stream>>>(x, xb, degi, w1l, w1r, w2l, w2r, bfr);
    deg_kernel<<<(N_EDGES + 255) / 256, 256, 0, stream>>>(ei, degi);
    scanA_kernel<<<SCAN_BLOCKS, 256, 0, stream>>>(degi, partial);
    scanB_kernel<<<1, 256, 0, stream>>>(partial, row_ptr);
    scanC_kernel<<<SCAN_BLOCKS, 256, 0, stream>>>(degi, partial, row_ptr, cursor);
    fill_kernel<<<(N_EDGES + 255) / 256, 256, 0, stream>>>(ei, cursor, csr);

    gather1_kernel<<<(N_NODES + 3) / 4, 256, 0, stream>>>(row_ptr, csr, xb, mean);
    fused_kernel<<<(N_NODES + 63) / 64, 256, 0, stream>>>(mean, x, B1a, B1b, B2,
                                                          b1, b2, pbb, out);
    gather2_kernel<<<(N_NODES + 3) / 4, 256, 0, stream>>>(row_ptr, csr, pbb, out);
}

// Round 9
// 152.625 us; speedup vs baseline: 1.1152x; 1.1152x over previous
//
#include <hip/hip_runtime.h>

#define N_NODES 50000
#define N_EDGES 600000
#define DIN 128
#define HD 128
#define DOUT 64
#define SCAN_BLOCKS 196  // ceil(50000/256)

typedef float f32x4 __attribute__((ext_vector_type(4)));
typedef short bf16x8 __attribute__((ext_vector_type(8)));

__device__ __forceinline__ unsigned short f2bf(float f) {
    unsigned u = __float_as_uint(f);
    unsigned r = (u + 0x7FFFu + ((u >> 16) & 1u)) >> 16;
    return (unsigned short)r;
}
__device__ __forceinline__ float bf2f(unsigned short s) {
    return __uint_as_float(((unsigned)s) << 16);
}

// ---------------- merged prep: xcvt (6250 blk) | zero degi (196) | bprep (192)
__global__ __launch_bounds__(256) void prep_kernel(const float* __restrict__ x,
                                                   unsigned short* __restrict__ xb,
                                                   int* __restrict__ degi,
                                                   const float* __restrict__ w1l,
                                                   const float* __restrict__ w1r,
                                                   const float* __restrict__ w2l,
                                                   const float* __restrict__ w2r,
                                                   unsigned short* __restrict__ bfr) {
    int gid = blockIdx.x;
    if (gid < 6250) {                    // x -> bf16, exact
        int i = gid * 256 + threadIdx.x;
        float4 v = ((const float4*)x)[i];
        ushort4 o;
        o.x = f2bf(v.x); o.y = f2bf(v.y); o.z = f2bf(v.z); o.w = f2bf(v.w);
        ((ushort4*)xb)[i] = o;
    } else if (gid < 6250 + 196) {       // zero degi
        int i = (gid - 6250) * 256 + threadIdx.x;
        if (i < N_NODES) degi[i] = 0;
    } else {                             // weight fragment prep
        int tid = (gid - 6446) * 256 + threadIdx.x;  // < 3*16384
        int a = tid >> 14;
        int r = tid & 16383;
        int j = r & 7, lane = (r >> 3) & 63, kc = (r >> 9) & 3, ct = r >> 11;
        int k = kc * 32 + ((lane >> 4) << 3) + j;
        int c = (ct << 4) + (lane & 15);
        float v;
        if (a == 0) v = w1l[k * HD + c];
        else if (a == 1) v = w1r[k * HD + c];
        else v = (c < 64) ? w2l[k * DOUT + c] : w2r[k * DOUT + (c - 64)];
        bfr[tid] = f2bf(v);
    }
}

// ---------------- degree histogram (int) ----------------
__global__ __launch_bounds__(256) void deg_kernel(const int* __restrict__ ei,
                                                  int* __restrict__ degi) {
    int e = blockIdx.x * 256 + threadIdx.x;
    if (e < N_EDGES) atomicAdd(&degi[ei[N_EDGES + e]], 1);
}

// ---------------- scan phase A: per-block (256-elem) sums ----------------
__global__ __launch_bounds__(256) void scanA_kernel(const int* __restrict__ degi,
                                                    int* __restrict__ partial) {
    int i = blockIdx.x * 256 + threadIdx.x;
    int v = (i < N_NODES) ? degi[i] : 0;
#pragma unroll
    for (int off = 32; off > 0; off >>= 1) v += __shfl_down(v, (unsigned)off, 64);
    __shared__ int ws[4];
    const int lane = threadIdx.x & 63, wid = threadIdx.x >> 6;
    if (lane == 0) ws[wid] = v;
    __syncthreads();
    if (threadIdx.x == 0) partial[blockIdx.x] = ws[0] + ws[1] + ws[2] + ws[3];
}

// ---------------- scan phase B: 1 block scans the partials ----------------
__global__ __launch_bounds__(256) void scanB_kernel(int* __restrict__ partial,
                                                    int* __restrict__ row_ptr) {
    const int lane = threadIdx.x & 63, wid = threadIdx.x >> 6;
    int i = threadIdx.x;
    int v = (i < SCAN_BLOCKS) ? partial[i] : 0;
    int incl = v;
#pragma unroll
    for (int off = 1; off < 64; off <<= 1) {
        int t = __shfl_up(incl, (unsigned)off, 64);
        if (lane >= off) incl += t;
    }
    __shared__ int ws[4];
    if (lane == 63) ws[wid] = incl;
    __syncthreads();
    int woff = 0;
    for (int w = 0; w < wid; w++) woff += ws[w];
    incl += woff;
    if (i < SCAN_BLOCKS) partial[i] = incl - v;
    if (i == 255) row_ptr[N_NODES] = incl;
}

// ---------------- scan phase C: local scan + block offset ----------------
__global__ __launch_bounds__(256) void scanC_kernel(const int* __restrict__ degi,
                                                    const int* __restrict__ partial,
                                                    int* __restrict__ row_ptr,
                                                    int* __restrict__ cursor) {
    const int lane = threadIdx.x & 63, wid = threadIdx.x >> 6;
    int i = blockIdx.x * 256 + threadIdx.x;
    int v = (i < N_NODES) ? degi[i] : 0;
    int incl = v;
#pragma unroll
    for (int off = 1; off < 64; off <<= 1) {
        int t = __shfl_up(incl, (unsigned)off, 64);
        if (lane >= off) incl += t;
    }
    __shared__ int ws[4];
    if (lane == 63) ws[wid] = incl;
    __syncthreads();
    int woff = 0;
    for (int w = 0; w < wid; w++) woff += ws[w];
    int excl = partial[blockIdx.x] + woff + incl - v;
    if (i < N_NODES) { row_ptr[i] = excl; cursor[i] = excl; }
}

// ---------------- CSR fill ----------------
__global__ __launch_bounds__(256) void fill_kernel(const int* __restrict__ ei,
                                                   int* __restrict__ cursor,
                                                   int* __restrict__ csr) {
    int e = blockIdx.x * 256 + threadIdx.x;
    if (e < N_EDGES) {
        int s = ei[e];
        int t = ei[N_EDGES + e];
        int pos = atomicAdd(&cursor[t], 1);
        csr[pos] = s;
    }
}

// ---------------- gather layer-1: 4 edge slots x 2 edges in flight (proven) ---
__global__ __launch_bounds__(256) void gather1_kernel(const int* __restrict__ row_ptr,
                                                      const int* __restrict__ csr,
                                                      const unsigned short* __restrict__ xb,
                                                      float* __restrict__ mean) {
    int node = blockIdx.x * 4 + (threadIdx.x >> 6);
    if (node >= N_NODES) return;
    const int lane = threadIdx.x & 63;
    const int g = lane >> 4;   // edge slot 0..3
    const int sl = lane & 15;  // dims [8*sl, 8*sl+8)
    int beg = row_ptr[node], end = row_ptr[node + 1];
    float acc[8] = {0.f, 0.f, 0.f, 0.f, 0.f, 0.f, 0.f, 0.f};
    int base = beg + g;
    for (; base + 4 < end; base += 8) {  // two independent loads per iter (MLP=2)
        int s0 = csr[base];
        int s1 = csr[base + 4];
        uint4 u0 = *(const uint4*)(xb + (size_t)s0 * DIN + sl * 8);
        uint4 u1 = *(const uint4*)(xb + (size_t)s1 * DIN + sl * 8);
        acc[0] += __uint_as_float(u0.x << 16) + __uint_as_float(u1.x << 16);
        acc[1] += __uint_as_float(u0.x & 0xffff0000u) + __uint_as_float(u1.x & 0xffff0000u);
        acc[2] += __uint_as_float(u0.y << 16) + __uint_as_float(u1.y << 16);
        acc[3] += __uint_as_float(u0.y & 0xffff0000u) + __uint_as_float(u1.y & 0xffff0000u);
        acc[4] += __uint_as_float(u0.z << 16) + __uint_as_float(u1.z << 16);
        acc[5] += __uint_as_float(u0.z & 0xffff0000u) + __uint_as_float(u1.z & 0xffff0000u);
        acc[6] += __uint_as_float(u0.w << 16) + __uint_as_float(u1.w << 16);
        acc[7] += __uint_as_float(u0.w & 0xffff0000u) + __uint_as_float(u1.w & 0xffff0000u);
    }
    if (base < end) {
        int s0 = csr[base];
        uint4 u = *(const uint4*)(xb + (size_t)s0 * DIN + sl * 8);
        acc[0] += __uint_as_float(u.x << 16);
        acc[1] += __uint_as_float(u.x & 0xffff0000u);
        acc[2] += __uint_as_float(u.y << 16);
        acc[3] += __uint_as_float(u.y & 0xffff0000u);
        acc[4] += __uint_as_float(u.z << 16);
        acc[5] += __uint_as_float(u.z & 0xffff0000u);
        acc[6] += __uint_as_float(u.w << 16);
        acc[7] += __uint_as_float(u.w & 0xffff0000u);
    }
#pragma unroll
    for (int i = 0; i < 8; i++) {
        acc[i] += __shfl_xor(acc[i], 16, 64);
        acc[i] += __shfl_xor(acc[i], 32, 64);
    }
    float r0, r1;
    if (g == 0)      { r0 = acc[0]; r1 = acc[1]; }
    else if (g == 1) { r0 = acc[2]; r1 = acc[3]; }
    else if (g == 2) { r0 = acc[4]; r1 = acc[5]; }
    else             { r0 = acc[6]; r1 = acc[7]; }
    float invd = 1.0f / fmaxf((float)(end - beg), 1.0f);
    float2 r; r.x = r0 * invd; r.y = r1 * invd;
    *(float2*)(mean + (size_t)node * DIN + sl * 8 + g * 2) = r;
}

// ---------------- fused MFMA, single-bf16 A (no hi/lo split), B from global ---
// h=relu(mean@w1l + x@w1r + b1); p=h@w2l; out=h@w2r+b2
__global__ __launch_bounds__(256) void fused_kernel(
    const float* __restrict__ mean, const float* __restrict__ x,
    const unsigned short* __restrict__ B1a, const unsigned short* __restrict__ B1b,
    const unsigned short* __restrict__ B2,
    const float* __restrict__ b1, const float* __restrict__ b2,
    unsigned short* __restrict__ pb, float* __restrict__ out) {
    __shared__ unsigned short Ahi[64 * 128];   // 16 KB (single plane)
    const int block0 = blockIdx.x * 64;
    const int tid = threadIdx.x;
    const int lane = tid & 63;
    const int wtile = tid >> 6;

    // --- T14: issue global loads for both A-tiles up-front (registers) ---
    float4 mv[8], xv[8];
#pragma unroll
    for (int i = 0; i < 8; i++) {
        int f = tid + i * 256;
        int row = f >> 5;
        int c4 = f & 31;
        int rg = block0 + row;
        if (rg >= N_NODES) rg = N_NODES - 1;
        mv[i] = *(const float4*)(mean + (size_t)rg * 128 + c4 * 4);
        xv[i] = *(const float4*)(x + (size_t)rg * 128 + c4 * 4);
    }

    f32x4 acc[8];
#pragma unroll
    for (int t = 0; t < 8; t++) acc[t] = (f32x4){0.f, 0.f, 0.f, 0.f};

    auto write_tile = [&](const float4* v8) {
#pragma unroll
        for (int i = 0; i < 8; i++) {
            int f = tid + i * 256;
            int row = f >> 5;
            int c4 = f & 31;
            float4 v = v8[i];
            ushort4 hi;
            hi.x = f2bf(v.x); hi.y = f2bf(v.y); hi.z = f2bf(v.z); hi.w = f2bf(v.w);
            int byte = row * 256 + ((c4 * 8) ^ ((row & 7) << 4));
            *(ushort4*)((char*)Ahi + byte) = hi;
        }
    };

    auto compute = [&](const unsigned short* __restrict__ Bf) {
        const int arow = wtile * 16 + (lane & 15);
        const int swz = (arow & 7) << 4;
#pragma unroll
        for (int kc = 0; kc < 4; kc++) {
            int byte = arow * 256 + ((kc * 64 + ((lane >> 4) << 4)) ^ swz);
            bf16x8 a = *(const bf16x8*)((const char*)Ahi + byte);
#pragma unroll
            for (int ct = 0; ct < 8; ct++) {
                bf16x8 b = *(const bf16x8*)(Bf + ((((ct << 2) + kc) << 6) + lane) * 8);
                acc[ct] = __builtin_amdgcn_mfma_f32_16x16x32_bf16(a, b, acc[ct], 0, 0, 0);
            }
        }
    };

    write_tile(mv);                 // waits only on mv loads
    __syncthreads();
    compute(B1a);                   // mean @ w1l   (x loads still in flight)
    __syncthreads();
    write_tile(xv);
    __syncthreads();
    compute(B1b);                   // + x @ w1r

    // epilogue 1: h = relu(acc + b1) -> restage single bf16.
    // No barrier needed: each wave's epilogue writes and compute reads touch
    // only its own 16 rows (arow, r0 both in [wtile*16, wtile*16+16)).
    {
        const int r0 = wtile * 16 + ((lane >> 4) << 2);
#pragma unroll
        for (int ct = 0; ct < 8; ct++) {
            int col = (ct << 4) + (lane & 15);
            float bv = b1[col];
#pragma unroll
            for (int r = 0; r < 4; r++) {
                float v = fmaxf(acc[ct][r] + bv, 0.f);
                int row = r0 + r;
                int byte = row * 256 + ((col * 2) ^ ((row & 7) << 4));
                *(unsigned short*)((char*)Ahi + byte) = f2bf(v);
            }
            acc[ct] = (f32x4){0.f, 0.f, 0.f, 0.f};
        }
    }
    compute(B2);                    // h @ [w2l | w2r]

    // epilogue 2: cols 0-63 -> pb (bf16), cols 64-127 -> out (+b2, f32)
    {
        const int r0 = wtile * 16 + ((lane >> 4) << 2);
#pragma unroll
        for (int ct = 0; ct < 8; ct++) {
            int col = (ct << 4) + (lane & 15);
#pragma unroll
            for (int r = 0; r < 4; r++) {
                int node = block0 + r0 + r;
                if (node < N_NODES) {
                    if (ct < 4) pb[(size_t)node * DOUT + col] = f2bf(acc[ct][r]);
                    else out[(size_t)node * DOUT + (col - 64)] = acc[ct][r] + b2[col - 64];
                }
            }
        }
    }
}

// ---------------- gather layer-2: 8 edge slots x 2 edges in flight (proven) ---
__global__ __launch_bounds__(256) void gather2_kernel(const int* __restrict__ row_ptr,
                                                      const int* __restrict__ csr,
                                                      const unsigned short* __restrict__ pb,
                                                      float* __restrict__ out) {
    int node = blockIdx.x * 4 + (threadIdx.x >> 6);
    if (node >= N_NODES) return;
    const int lane = threadIdx.x & 63;
    const int g = lane >> 3;  // edge slot 0..7
    const int sl = lane & 7;  // dims [8*sl, 8*sl+8)
    int beg = row_ptr[node], end = row_ptr[node + 1];
    float acc[8] = {0.f, 0.f, 0.f, 0.f, 0.f, 0.f, 0.f, 0.f};
    int base = beg + g;
    for (; base + 8 < end; base += 16) {  // two independent loads per iter
        int s0 = csr[base];
        int s1 = csr[base + 8];
        uint4 u0 = *(const uint4*)(pb + (size_t)s0 * DOUT + sl * 8);
        uint4 u1 = *(const uint4*)(pb + (size_t)s1 * DOUT + sl * 8);
        acc[0] += __uint_as_float(u0.x << 16) + __uint_as_float(u1.x << 16);
        acc[1] += __uint_as_float(u0.x & 0xffff0000u) + __uint_as_float(u1.x & 0xffff0000u);
        acc[2] += __uint_as_float(u0.y << 16) + __uint_as_float(u1.y << 16);
        acc[3] += __uint_as_float(u0.y & 0xffff0000u) + __uint_as_float(u1.y & 0xffff0000u);
        acc[4] += __uint_as_float(u0.z << 16) + __uint_as_float(u1.z << 16);
        acc[5] += __uint_as_float(u0.z & 0xffff0000u) + __uint_as_float(u1.z & 0xffff0000u);
        acc[6] += __uint_as_float(u0.w << 16) + __uint_as_float(u1.w << 16);
        acc[7] += __uint_as_float(u0.w & 0xffff0000u) + __uint_as_float(u1.w & 0xffff0000u);
    }
    if (base < end) {
        int s0 = csr[base];
        uint4 u = *(const uint4*)(pb + (size_t)s0 * DOUT + sl * 8);
        acc[0] += __uint_as_float(u.x << 16);
        acc[1] += __uint_as_float(u.x & 0xffff0000u);
        acc[2] += __uint_as_float(u.y << 16);
        acc[3] += __uint_as_float(u.y & 0xffff0000u);
        acc[4] += __uint_as_float(u.z << 16);
        acc[5] += __uint_as_float(u.z & 0xffff0000u);
        acc[6] += __uint_as_float(u.w << 16);
        acc[7] += __uint_as_float(u.w & 0xffff0000u);
    }
#pragma unroll
    for (int i = 0; i < 8; i++) {
        acc[i] += __shfl_xor(acc[i], 8, 64);
        acc[i] += __shfl_xor(acc[i], 16, 64);
        acc[i] += __shfl_xor(acc[i], 32, 64);
    }
    float r;
    if (g == 0)      r = acc[0];
    else if (g == 1) r = acc[1];
    else if (g == 2) r = acc[2];
    else if (g == 3) r = acc[3];
    else if (g == 4) r = acc[4];
    else if (g == 5) r = acc[5];
    else if (g == 6) r = acc[6];
    else             r = acc[7];
    float invd = 1.0f / fmaxf((float)(end - beg), 1.0f);
    int d = sl * 8 + g;
    out[(size_t)node * DOUT + d] += r * invd;
}

extern "C" void kernel_launch(void* const* d_in, const int* in_sizes, int n_in,
                              void* d_out, int out_size, void* d_ws, size_t ws_size,
                              hipStream_t stream) {
    const float* x   = (const float*)d_in[0];
    const int*   ei  = (const int*)d_in[1];
    const float* w1l = (const float*)d_in[2];
    const float* b1  = (const float*)d_in[3];
    const float* w1r = (const float*)d_in[4];
    const float* w2l = (const float*)d_in[5];
    const float* b2  = (const float*)d_in[6];
    const float* w2r = (const float*)d_in[7];
    float* out = (float*)d_out;

    // workspace layout
    int* iw = (int*)d_ws;
    int* degi    = iw;                        // 50000
    int* row_ptr = iw + 50000;                // 50001
    int* cursor  = iw + 100001;               // 50000
    int* csr     = iw + 150001;               // 600000
    int* partial = iw + 750001;               // 256
    float* mean  = (float*)(iw + 750272);     // N*128 f32, 16B aligned
    unsigned short* xb  = (unsigned short*)(mean + (size_t)N_NODES * DIN);  // N*128 bf16
    unsigned short* pbb = xb + (size_t)N_NODES * DIN;                       // N*64 bf16
    unsigned short* bfr = pbb + (size_t)N_NODES * DOUT;                     // 3*16384 bf16
    const unsigned short* B1a = bfr;
    const unsigned short* B1b = bfr + 16384;
    const unsigned short* B2  = bfr + 32768;

    prep_kernel<<<6638, 256, 0, stream>>>(x, xb, degi, w1l, w1r, w2l, w2r, bfr);
    deg_kernel<<<(N_EDGES + 255) / 256, 256, 0, stream>>>(ei, degi);
    scanA_kernel<<<SCAN_BLOCKS, 256, 0, stream>>>(degi, partial);
    scanB_kernel<<<1, 256, 0, stream>>>(partial, row_ptr);
    scanC_kernel<<<SCAN_BLOCKS, 256, 0, stream>>>(degi, partial, row_ptr, cursor);
    fill_kernel<<<(N_EDGES + 255) / 256, 256, 0, stream>>>(ei, cursor, csr);

    gather1_kernel<<<(N_NODES + 3) / 4, 256, 0, stream>>>(row_ptr, csr, xb, mean);
    fused_kernel<<<(N_NODES + 63) / 64, 256, 0, stream>>>(mean, x, B1a, B1b, B2,
                                                          b1, b2, pbb, out);
    gather2_kernel<<<(N_NODES + 3) / 4, 256, 0, stream>>>(row_ptr, csr, pbb, out);
}